// Round 2
// baseline (2616.865 us; speedup 1.0000x reference)
//
#include <hip/hip_runtime.h>

// ---------------------------------------------------------------------------
// GCN encoder: 3x { GEMM -> SpMM } with BN+ReLU fused into GEMM input loads.
// CSR built on-device each launch (histogram -> single-block scan -> scatter).
// ---------------------------------------------------------------------------

__global__ void hist_kernel(const int* __restrict__ row, int* __restrict__ rowptr, int E) {
    int i = blockIdx.x * blockDim.x + threadIdx.x;
    int stride = gridDim.x * blockDim.x;
    for (; i < E; i += stride) atomicAdd(&rowptr[row[i] + 1], 1);
}

// Single-block inclusive scan of rowptr[0..n-1]; also writes cursor[i]=rowptr[i]
// (start of row i) for the scatter pass. n = N+1.
__global__ __launch_bounds__(1024) void scan_kernel(int* __restrict__ rowptr,
                                                    int* __restrict__ cursor,
                                                    int n, int N) {
    __shared__ int warp_sums[16];
    __shared__ int s_run;
    int t = threadIdx.x;
    int wid = t >> 6, lane = t & 63;
    if (t == 0) s_run = 0;
    __syncthreads();
    const int CHUNK = 1024 * 8;
    for (int base = 0; base < n; base += CHUNK) {
        int v[8];
        int local = 0;
        int i0 = base + t * 8;
#pragma unroll
        for (int j = 0; j < 8; ++j) {
            int idx = i0 + j;
            v[j] = (idx < n) ? rowptr[idx] : 0;
            local += v[j];
        }
        // wave-inclusive scan of per-thread sums
        int x = local;
#pragma unroll
        for (int off = 1; off < 64; off <<= 1) {
            int y = __shfl_up(x, off);
            if (lane >= off) x += y;
        }
        if (lane == 63) warp_sums[wid] = x;
        __syncthreads();
        if (wid == 0) {
            int w = (lane < 16) ? warp_sums[lane] : 0;
#pragma unroll
            for (int off = 1; off < 16; off <<= 1) {
                int y = __shfl_up(w, off);
                if (lane >= off) w += y;
            }
            if (lane < 16) warp_sums[lane] = w;
        }
        __syncthreads();
        int wave_off = (wid > 0) ? warp_sums[wid - 1] : 0;
        int chunk_total = warp_sums[15];
        int acc = (x - local) + wave_off + s_run;  // exclusive prefix for this thread
#pragma unroll
        for (int j = 0; j < 8; ++j) {
            int idx = i0 + j;
            acc += v[j];  // inclusive at idx
            if (idx < n) {
                rowptr[idx] = acc;
                if (idx < N) cursor[idx] = acc;
            }
        }
        __syncthreads();
        if (t == 0) s_run += chunk_total;
        __syncthreads();
    }
}

__global__ void scatter_kernel(const int* __restrict__ row, const int* __restrict__ col,
                               const float* __restrict__ vals, int* __restrict__ cursor,
                               int* __restrict__ ccol, float* __restrict__ cval, int E) {
    int i = blockIdx.x * blockDim.x + threadIdx.x;
    int stride = gridDim.x * blockDim.x;
    for (; i < E; i += stride) {
        int r = row[i];
        int p = atomicAdd(&cursor[r], 1);
        ccol[p] = col[i];
        cval[p] = vals[i];
    }
}

// C[M,N] = act(A)[M,K] @ W[K,N] + bias.  If BN_APPLY: act(a)_k = relu(a*scale[k]+shift[k]).
// 64x64 tile, BK=16, 256 threads, 4x4 per thread.
template <bool BN_APPLY>
__global__ __launch_bounds__(256) void gemm_kernel(const float* __restrict__ A,
                                                   const float* __restrict__ W,
                                                   const float* __restrict__ bias,
                                                   const float* __restrict__ scale,
                                                   const float* __restrict__ shift,
                                                   float* __restrict__ C,
                                                   int M, int K, int N) {
    __shared__ float As[16][68];  // transposed A tile [k][m], padded
    __shared__ float Bs[16][64];
    int t = threadIdx.x;
    int tx = t & 15, ty = t >> 4;
    int row0 = blockIdx.x * 64;
    int n0 = blockIdx.y * 64;
    int lm = t >> 2;         // 0..63 : A tile row
    int lk = (t & 3) * 4;    // 0,4,8,12 : A tile k (float4)
    int lkb = t >> 4;        // 0..15 : B tile k
    int lnv = (t & 15) * 4;  // B tile n (float4)

    float acc[4][4] = {};
    for (int k0 = 0; k0 < K; k0 += 16) {
        float4 a4 = {0.f, 0.f, 0.f, 0.f};
        int gr = row0 + lm;
        if (gr < M) a4 = *(const float4*)(A + (size_t)gr * K + k0 + lk);
        if (BN_APPLY) {
            a4.x = fmaxf(a4.x * scale[k0 + lk + 0] + shift[k0 + lk + 0], 0.f);
            a4.y = fmaxf(a4.y * scale[k0 + lk + 1] + shift[k0 + lk + 1], 0.f);
            a4.z = fmaxf(a4.z * scale[k0 + lk + 2] + shift[k0 + lk + 2], 0.f);
            a4.w = fmaxf(a4.w * scale[k0 + lk + 3] + shift[k0 + lk + 3], 0.f);
        }
        As[lk + 0][lm] = a4.x;
        As[lk + 1][lm] = a4.y;
        As[lk + 2][lm] = a4.z;
        As[lk + 3][lm] = a4.w;
        *(float4*)&Bs[lkb][lnv] = *(const float4*)(W + (size_t)(k0 + lkb) * N + n0 + lnv);
        __syncthreads();
#pragma unroll
        for (int kk = 0; kk < 16; ++kk) {
            float4 av = *(const float4*)&As[kk][ty * 4];
            float4 bv = *(const float4*)&Bs[kk][tx * 4];
            acc[0][0] += av.x * bv.x; acc[0][1] += av.x * bv.y; acc[0][2] += av.x * bv.z; acc[0][3] += av.x * bv.w;
            acc[1][0] += av.y * bv.x; acc[1][1] += av.y * bv.y; acc[1][2] += av.y * bv.z; acc[1][3] += av.y * bv.w;
            acc[2][0] += av.z * bv.x; acc[2][1] += av.z * bv.y; acc[2][2] += av.z * bv.z; acc[2][3] += av.z * bv.w;
            acc[3][0] += av.w * bv.x; acc[3][1] += av.w * bv.y; acc[3][2] += av.w * bv.z; acc[3][3] += av.w * bv.w;
        }
        __syncthreads();
    }
#pragma unroll
    for (int i = 0; i < 4; ++i) {
        int gr = row0 + ty * 4 + i;
        if (gr < M) {
            float4 o;
            o.x = acc[i][0] + bias[n0 + tx * 4 + 0];
            o.y = acc[i][1] + bias[n0 + tx * 4 + 1];
            o.z = acc[i][2] + bias[n0 + tx * 4 + 2];
            o.w = acc[i][3] + bias[n0 + tx * 4 + 3];
            *(float4*)(C + (size_t)gr * N + n0 + tx * 4) = o;
        }
    }
}

// One wave per output row; 64 lanes cover F floats (float4 for F=256, float2 for F=128).
template <int F>
__global__ __launch_bounds__(256) void spmm_kernel(const int* __restrict__ rowptr,
                                                   const int* __restrict__ ccol,
                                                   const float* __restrict__ cval,
                                                   const float* __restrict__ H,
                                                   float* __restrict__ out, int M) {
    int wid = threadIdx.x >> 6;
    int lane = threadIdx.x & 63;
    int r = blockIdx.x * 4 + wid;
    if (r >= M) return;
    int e0 = rowptr[r], e1 = rowptr[r + 1];
    if (F == 256) {
        const float4* Hv = (const float4*)H;  // row stride 64 float4
        float4 acc = {0.f, 0.f, 0.f, 0.f};
        for (int e = e0; e < e1; ++e) {
            int c = ccol[e];
            float v = cval[e];
            float4 h = Hv[(size_t)c * 64 + lane];
            acc.x += v * h.x; acc.y += v * h.y; acc.z += v * h.z; acc.w += v * h.w;
        }
        ((float4*)out)[(size_t)r * 64 + lane] = acc;
    } else {
        const float2* Hv = (const float2*)H;  // row stride 64 float2
        float2 acc = {0.f, 0.f};
        for (int e = e0; e < e1; ++e) {
            int c = ccol[e];
            float v = cval[e];
            float2 h = Hv[(size_t)c * 64 + lane];
            acc.x += v * h.x; acc.y += v * h.y;
        }
        ((float2*)out)[(size_t)r * 64 + lane] = acc;
    }
}

// Per-column sum / sumsq over rows (column = threadIdx.x, 256 columns).
__global__ __launch_bounds__(256) void bn_stats_kernel(const float* __restrict__ H,
                                                       float* __restrict__ sums,
                                                       float* __restrict__ sumsq, int M) {
    int c = threadIdx.x;
    int nb = gridDim.x;
    int rows_per = (M + nb - 1) / nb;
    int r0 = blockIdx.x * rows_per;
    int r1 = min(M, r0 + rows_per);
    float s = 0.f, q = 0.f;
    for (int r = r0; r < r1; ++r) {
        float v = H[(size_t)r * 256 + c];
        s += v;
        q += v * v;
    }
    atomicAdd(&sums[c], s);
    atomicAdd(&sumsq[c], q);
}

__global__ void bn_finalize_kernel(const float* __restrict__ sums, const float* __restrict__ sumsq,
                                   const float* __restrict__ g, const float* __restrict__ be,
                                   float* __restrict__ scale, float* __restrict__ shift, int M) {
    int c = threadIdx.x;
    float mean = sums[c] / (float)M;
    float var = sumsq[c] / (float)M - mean * mean;
    float inv = rsqrtf(var + 1e-5f);
    float s = g[c] * inv;
    scale[c] = s;
    shift[c] = be[c] - mean * s;
}

extern "C" void kernel_launch(void* const* d_in, const int* in_sizes, int n_in,
                              void* d_out, int out_size, void* d_ws, size_t ws_size,
                              hipStream_t stream) {
    const float* x   = (const float*)d_in[0];
    const float* vals= (const float*)d_in[1];
    const float* W0  = (const float*)d_in[2];
    const float* b0  = (const float*)d_in[3];
    const float* g0  = (const float*)d_in[4];
    const float* be0 = (const float*)d_in[5];
    const float* W1  = (const float*)d_in[6];
    const float* b1  = (const float*)d_in[7];
    const float* g1  = (const float*)d_in[8];
    const float* be1 = (const float*)d_in[9];
    const float* W2  = (const float*)d_in[10];
    const float* b2  = (const float*)d_in[11];
    const int* row   = (const int*)d_in[12];
    const int* col   = (const int*)d_in[13];
    const int E = in_sizes[1];
    const int M = in_sizes[0] / 256;
    float* out = (float*)d_out;

    char* ws = (char*)d_ws;
    size_t off = 0;
    auto alloc = [&](size_t bytes) -> void* {
        void* p = ws + off;
        off += (bytes + 255) & ~(size_t)255;
        return p;
    };
    float* hA    = (float*)alloc((size_t)M * 256 * 4);
    float* hB    = (float*)alloc((size_t)M * 256 * 4);
    float* cval  = (float*)alloc((size_t)E * 4);
    int*   ccol  = (int*)alloc((size_t)E * 4);
    int*   rowptr= (int*)alloc((size_t)(M + 1) * 4);
    int*   cursor= (int*)alloc((size_t)M * 4);
    float* sums  = (float*)alloc(256 * 4);
    float* sumsq = (float*)alloc(256 * 4);  // contiguous after sums
    float* scale = (float*)alloc(256 * 4);
    float* shift = (float*)alloc(256 * 4);

    // --- CSR build ---
    hipMemsetAsync(rowptr, 0, (size_t)(M + 1) * 4, stream);
    hist_kernel<<<2048, 256, 0, stream>>>(row, rowptr, E);
    scan_kernel<<<1, 1024, 0, stream>>>(rowptr, cursor, M + 1, M);
    scatter_kernel<<<2048, 256, 0, stream>>>(row, col, vals, cursor, ccol, cval, E);

    dim3 gemm_grid((M + 63) / 64, 4);
    int spmm_grid = (M + 3) / 4;

    // --- layer 0: h = spmm(x @ W0 + b0) ---
    gemm_kernel<false><<<gemm_grid, 256, 0, stream>>>(x, W0, b0, nullptr, nullptr, hA, M, 256, 256);
    spmm_kernel<256><<<spmm_grid, 256, 0, stream>>>(rowptr, ccol, cval, hA, hB, M);

    // BN0 stats; affine+relu fused into GEMM1 input
    hipMemsetAsync(sums, 0, 2048, stream);
    bn_stats_kernel<<<256, 256, 0, stream>>>(hB, sums, sumsq, M);
    bn_finalize_kernel<<<1, 256, 0, stream>>>(sums, sumsq, g0, be0, scale, shift, M);

    // --- layer 1 ---
    gemm_kernel<true><<<gemm_grid, 256, 0, stream>>>(hB, W1, b1, scale, shift, hA, M, 256, 256);
    spmm_kernel<256><<<spmm_grid, 256, 0, stream>>>(rowptr, ccol, cval, hA, hB, M);

    hipMemsetAsync(sums, 0, 2048, stream);
    bn_stats_kernel<<<256, 256, 0, stream>>>(hB, sums, sumsq, M);
    bn_finalize_kernel<<<1, 256, 0, stream>>>(sums, sumsq, g1, be1, scale, shift, M);

    // --- layer 2: out = spmm(relu(bn(h)) @ W2 + b2), F=128 ---
    gemm_kernel<true><<<dim3((M + 63) / 64, 2), 256, 0, stream>>>(hB, W2, b2, scale, shift, hA, M, 256, 128);
    spmm_kernel<128><<<spmm_grid, 256, 0, stream>>>(rowptr, ccol, cval, hA, out, M);
}

// Round 3
// 2326.517 us; speedup vs baseline: 1.1248x; 1.1248x over previous
//
#include <hip/hip_runtime.h>

// ---------------------------------------------------------------------------
// GCN encoder: 3x { split-bf16 MFMA GEMM -> SpMM } with BN+ReLU fused into
// GEMM input staging. CSR built on-device each launch.
// fp32 A,W are split A = hi + lo (bf16 each); A@W ~= Ah@Wh + Ah@Wl + Al@Wh
// (lo*lo term ~2^-16 relative, dropped). MFMA accumulates in fp32.
// ---------------------------------------------------------------------------

typedef __attribute__((ext_vector_type(8))) short s8b;   // 8 bf16 (4 VGPRs)
typedef __attribute__((ext_vector_type(4))) float f32x4; // MFMA accumulator

__device__ inline unsigned short bf16_rne(float f) {
    unsigned u = __float_as_uint(f);
    return (unsigned short)((u + 0x7fffu + ((u >> 16) & 1u)) >> 16);
}
__device__ inline float bf16_to_f(unsigned short h) {
    return __uint_as_float((unsigned)h << 16);
}

// ---------------------------- CSR build ------------------------------------
__global__ void hist_kernel(const int* __restrict__ row, int* __restrict__ rowptr, int E) {
    int i = blockIdx.x * blockDim.x + threadIdx.x;
    int stride = gridDim.x * blockDim.x;
    for (; i < E; i += stride) atomicAdd(&rowptr[row[i] + 1], 1);
}

__global__ __launch_bounds__(1024) void scan_kernel(int* __restrict__ rowptr,
                                                    int* __restrict__ cursor,
                                                    int n, int N) {
    __shared__ int warp_sums[16];
    __shared__ int s_run;
    int t = threadIdx.x;
    int wid = t >> 6, lane = t & 63;
    if (t == 0) s_run = 0;
    __syncthreads();
    const int CHUNK = 1024 * 8;
    for (int base = 0; base < n; base += CHUNK) {
        int v[8];
        int local = 0;
        int i0 = base + t * 8;
#pragma unroll
        for (int j = 0; j < 8; ++j) {
            int idx = i0 + j;
            v[j] = (idx < n) ? rowptr[idx] : 0;
            local += v[j];
        }
        int x = local;
#pragma unroll
        for (int off = 1; off < 64; off <<= 1) {
            int y = __shfl_up(x, off);
            if (lane >= off) x += y;
        }
        if (lane == 63) warp_sums[wid] = x;
        __syncthreads();
        if (wid == 0) {
            int w = (lane < 16) ? warp_sums[lane] : 0;
#pragma unroll
            for (int off = 1; off < 16; off <<= 1) {
                int y = __shfl_up(w, off);
                if (lane >= off) w += y;
            }
            if (lane < 16) warp_sums[lane] = w;
        }
        __syncthreads();
        int wave_off = (wid > 0) ? warp_sums[wid - 1] : 0;
        int chunk_total = warp_sums[15];
        int acc = (x - local) + wave_off + s_run;
#pragma unroll
        for (int j = 0; j < 8; ++j) {
            int idx = i0 + j;
            acc += v[j];
            if (idx < n) {
                rowptr[idx] = acc;
                if (idx < N) cursor[idx] = acc;
            }
        }
        __syncthreads();
        if (t == 0) s_run += chunk_total;
        __syncthreads();
    }
}

__global__ void scatter_kernel(const int* __restrict__ row, const int* __restrict__ col,
                               const float* __restrict__ vals, int* __restrict__ cursor,
                               int* __restrict__ ccol, float* __restrict__ cval, int E) {
    int i = blockIdx.x * blockDim.x + threadIdx.x;
    int stride = gridDim.x * blockDim.x;
    for (; i < E; i += stride) {
        int r = row[i];
        int p = atomicAdd(&cursor[r], 1);
        ccol[p] = col[i];
        cval[p] = vals[i];
    }
}

// ------------------- W preprocessing: transpose + bf16 split ---------------
// Wt_hi/Wt_lo are [N][K] (K=256), row-major over n.
__global__ void wsplit_kernel(const float* __restrict__ W, short* __restrict__ Wt_hi,
                              short* __restrict__ Wt_lo, int N) {
    const int K = 256;
    int i = blockIdx.x * blockDim.x + threadIdx.x;
    if (i >= K * N) return;
    int k = i / N, n = i % N;
    float f = W[i];
    unsigned short h = bf16_rne(f);
    unsigned short l = bf16_rne(f - bf16_to_f(h));
    Wt_hi[(size_t)n * K + k] = (short)h;
    Wt_lo[(size_t)n * K + k] = (short)l;
}

// --------------------------- MFMA GEMM -------------------------------------
// C[M,N] = act(A)[M,256] @ W[256,N] + bias, act = optional BN affine + ReLU.
// Block: 128x128 tile, 4 waves in 2x2, each wave 64x64 (4x4 16x16 frags).
template <bool BN_APPLY>
__global__ __launch_bounds__(256) void gemm_mfma_kernel(
    const float* __restrict__ A, const short* __restrict__ Wth,
    const short* __restrict__ Wtl, const float* __restrict__ bias,
    const float* __restrict__ scale, const float* __restrict__ shift,
    float* __restrict__ C, int M, int N) {
    const int K = 256;
    const int LDT = 40;  // padded k-stride (bf16 elems): row stride 80B spreads banks
    __shared__ short Ah[128 * LDT], Al[128 * LDT], Bh[128 * LDT], Bl[128 * LDT];

    int t = threadIdx.x;
    int wave = t >> 6, lane = t & 63;
    int wm = wave >> 1, wn = wave & 1;
    int row0 = blockIdx.x * 128;
    int n0 = blockIdx.y * 128;

    int srow = t >> 1;           // 0..127 (A tile row / B tile n)
    int skh = (t & 1) * 16;      // k offset within the 32-wide K-step

    int lr = lane & 15;
    int lg = (lane >> 4) * 8;    // k-group offset within frag

    f32x4 acc[4][4];
#pragma unroll
    for (int i = 0; i < 4; ++i)
#pragma unroll
        for (int j = 0; j < 4; ++j) acc[i][j] = (f32x4){0.f, 0.f, 0.f, 0.f};

    for (int k0 = 0; k0 < K; k0 += 32) {
        // ---- stage A: load fp32, BN+ReLU, split to hi/lo bf16 ----
        float va[16];
        int gr = row0 + srow;
        if (gr < M) {
            const float4* ap = (const float4*)(A + (size_t)gr * K + k0 + skh);
#pragma unroll
            for (int q = 0; q < 4; ++q) {
                float4 v = ap[q];
                va[4 * q + 0] = v.x; va[4 * q + 1] = v.y;
                va[4 * q + 2] = v.z; va[4 * q + 3] = v.w;
            }
        } else {
#pragma unroll
            for (int q = 0; q < 16; ++q) va[q] = 0.f;
        }
        if (BN_APPLY) {
#pragma unroll
            for (int q = 0; q < 4; ++q) {
                float4 sc = *(const float4*)(scale + k0 + skh + 4 * q);
                float4 sh = *(const float4*)(shift + k0 + skh + 4 * q);
                va[4 * q + 0] = fmaxf(va[4 * q + 0] * sc.x + sh.x, 0.f);
                va[4 * q + 1] = fmaxf(va[4 * q + 1] * sc.y + sh.y, 0.f);
                va[4 * q + 2] = fmaxf(va[4 * q + 2] * sc.z + sh.z, 0.f);
                va[4 * q + 3] = fmaxf(va[4 * q + 3] * sc.w + sh.w, 0.f);
            }
        }
        s8b vh0, vl0, vh1, vl1;
#pragma unroll
        for (int q = 0; q < 8; ++q) {
            unsigned short h = bf16_rne(va[q]);
            vh0[q] = (short)h;
            vl0[q] = (short)bf16_rne(va[q] - bf16_to_f(h));
        }
#pragma unroll
        for (int q = 0; q < 8; ++q) {
            unsigned short h = bf16_rne(va[8 + q]);
            vh1[q] = (short)h;
            vl1[q] = (short)bf16_rne(va[8 + q] - bf16_to_f(h));
        }
        *(s8b*)&Ah[srow * LDT + skh]     = vh0;
        *(s8b*)&Ah[srow * LDT + skh + 8] = vh1;
        *(s8b*)&Al[srow * LDT + skh]     = vl0;
        *(s8b*)&Al[srow * LDT + skh + 8] = vl1;

        // ---- stage B: pre-split W^T, straight bf16 copies ----
        int gn = n0 + srow;  // N is a multiple of 128 here (256 or 128)
        const s8b* wph = (const s8b*)(Wth + (size_t)gn * K + k0 + skh);
        const s8b* wpl = (const s8b*)(Wtl + (size_t)gn * K + k0 + skh);
        s8b wh0 = wph[0], wh1 = wph[1];
        s8b wl0 = wpl[0], wl1 = wpl[1];
        *(s8b*)&Bh[srow * LDT + skh]     = wh0;
        *(s8b*)&Bh[srow * LDT + skh + 8] = wh1;
        *(s8b*)&Bl[srow * LDT + skh]     = wl0;
        *(s8b*)&Bl[srow * LDT + skh + 8] = wl1;
        __syncthreads();

        // ---- fragments + MFMA ----
        s8b afh[4], afl[4], bfh[4], bfl[4];
#pragma unroll
        for (int i = 0; i < 4; ++i) {
            int r = (wm * 64 + i * 16 + lr) * LDT + lg;
            afh[i] = *(const s8b*)&Ah[r];
            afl[i] = *(const s8b*)&Al[r];
        }
#pragma unroll
        for (int j = 0; j < 4; ++j) {
            int c = (wn * 64 + j * 16 + lr) * LDT + lg;
            bfh[j] = *(const s8b*)&Bh[c];
            bfl[j] = *(const s8b*)&Bl[c];
        }
#pragma unroll
        for (int i = 0; i < 4; ++i)
#pragma unroll
            for (int j = 0; j < 4; ++j) {
                acc[i][j] = __builtin_amdgcn_mfma_f32_16x16x32_bf16(afh[i], bfh[j], acc[i][j], 0, 0, 0);
                acc[i][j] = __builtin_amdgcn_mfma_f32_16x16x32_bf16(afh[i], bfl[j], acc[i][j], 0, 0, 0);
                acc[i][j] = __builtin_amdgcn_mfma_f32_16x16x32_bf16(afl[i], bfh[j], acc[i][j], 0, 0, 0);
            }
        __syncthreads();
    }

    // ---- epilogue: C = acc + bias. C/D layout: col=lane&15, row=4*(lane>>4)+reg ----
    int lq = lane >> 4;
#pragma unroll
    for (int j = 0; j < 4; ++j) {
        int colg = n0 + wn * 64 + j * 16 + lr;
        float bb = bias[colg];
#pragma unroll
        for (int i = 0; i < 4; ++i) {
#pragma unroll
            for (int r = 0; r < 4; ++r) {
                int rowg = row0 + wm * 64 + i * 16 + lq * 4 + r;
                if (rowg < M) C[(size_t)rowg * N + colg] = acc[i][j][r] + bb;
            }
        }
    }
}

// ------------------------------- SpMM --------------------------------------
template <int F>
__global__ __launch_bounds__(256) void spmm_kernel(const int* __restrict__ rowptr,
                                                   const int* __restrict__ ccol,
                                                   const float* __restrict__ cval,
                                                   const float* __restrict__ H,
                                                   float* __restrict__ out, int M) {
    int wid = threadIdx.x >> 6;
    int lane = threadIdx.x & 63;
    int r = blockIdx.x * 4 + wid;
    if (r >= M) return;
    int e0 = rowptr[r], e1 = rowptr[r + 1];
    if (F == 256) {
        const float4* Hv = (const float4*)H;
        float4 acc = {0.f, 0.f, 0.f, 0.f};
        for (int e = e0; e < e1; ++e) {
            int c = ccol[e];
            float v = cval[e];
            float4 h = Hv[(size_t)c * 64 + lane];
            acc.x += v * h.x; acc.y += v * h.y; acc.z += v * h.z; acc.w += v * h.w;
        }
        ((float4*)out)[(size_t)r * 64 + lane] = acc;
    } else {
        const float2* Hv = (const float2*)H;
        float2 acc = {0.f, 0.f};
        for (int e = e0; e < e1; ++e) {
            int c = ccol[e];
            float v = cval[e];
            float2 h = Hv[(size_t)c * 64 + lane];
            acc.x += v * h.x; acc.y += v * h.y;
        }
        ((float2*)out)[(size_t)r * 64 + lane] = acc;
    }
}

// ------------------------------- BN ----------------------------------------
__global__ __launch_bounds__(256) void bn_stats_kernel(const float* __restrict__ H,
                                                       float* __restrict__ sums,
                                                       float* __restrict__ sumsq, int M) {
    int c = threadIdx.x;
    int nb = gridDim.x;
    int rows_per = (M + nb - 1) / nb;
    int r0 = blockIdx.x * rows_per;
    int r1 = min(M, r0 + rows_per);
    float s = 0.f, q = 0.f;
    for (int r = r0; r < r1; ++r) {
        float v = H[(size_t)r * 256 + c];
        s += v;
        q += v * v;
    }
    atomicAdd(&sums[c], s);
    atomicAdd(&sumsq[c], q);
}

__global__ void bn_finalize_kernel(const float* __restrict__ sums, const float* __restrict__ sumsq,
                                   const float* __restrict__ g, const float* __restrict__ be,
                                   float* __restrict__ scale, float* __restrict__ shift, int M) {
    int c = threadIdx.x;
    float mean = sums[c] / (float)M;
    float var = sumsq[c] / (float)M - mean * mean;
    float inv = rsqrtf(var + 1e-5f);
    float s = g[c] * inv;
    scale[c] = s;
    shift[c] = be[c] - mean * s;
}

extern "C" void kernel_launch(void* const* d_in, const int* in_sizes, int n_in,
                              void* d_out, int out_size, void* d_ws, size_t ws_size,
                              hipStream_t stream) {
    const float* x   = (const float*)d_in[0];
    const float* vals= (const float*)d_in[1];
    const float* W0  = (const float*)d_in[2];
    const float* b0  = (const float*)d_in[3];
    const float* g0  = (const float*)d_in[4];
    const float* be0 = (const float*)d_in[5];
    const float* W1  = (const float*)d_in[6];
    const float* b1  = (const float*)d_in[7];
    const float* g1  = (const float*)d_in[8];
    const float* be1 = (const float*)d_in[9];
    const float* W2  = (const float*)d_in[10];
    const float* b2  = (const float*)d_in[11];
    const int* row   = (const int*)d_in[12];
    const int* col   = (const int*)d_in[13];
    const int E = in_sizes[1];
    const int M = in_sizes[0] / 256;
    float* out = (float*)d_out;

    char* ws = (char*)d_ws;
    size_t off = 0;
    auto alloc = [&](size_t bytes) -> void* {
        void* p = ws + off;
        off += (bytes + 255) & ~(size_t)255;
        return p;
    };
    float* hA    = (float*)alloc((size_t)M * 256 * 4);
    float* hB    = (float*)alloc((size_t)M * 256 * 4);
    float* cval  = (float*)alloc((size_t)E * 4);
    int*   ccol  = (int*)alloc((size_t)E * 4);
    int*   rowptr= (int*)alloc((size_t)(M + 1) * 4);
    int*   cursor= (int*)alloc((size_t)M * 4);
    float* sums  = (float*)alloc(256 * 4);
    float* sumsq = (float*)alloc(256 * 4);
    float* scale = (float*)alloc(256 * 4);
    float* shift = (float*)alloc(256 * 4);
    short* Wth   = (short*)alloc((size_t)256 * 256 * 2);
    short* Wtl   = (short*)alloc((size_t)256 * 256 * 2);

    // --- CSR build ---
    hipMemsetAsync(rowptr, 0, (size_t)(M + 1) * 4, stream);
    hist_kernel<<<2048, 256, 0, stream>>>(row, rowptr, E);
    scan_kernel<<<1, 1024, 0, stream>>>(rowptr, cursor, M + 1, M);
    scatter_kernel<<<2048, 256, 0, stream>>>(row, col, vals, cursor, ccol, cval, E);

    int gx = (M + 127) / 128;
    int spmm_grid = (M + 3) / 4;

    // --- layer 0 ---
    wsplit_kernel<<<(256 * 256 + 255) / 256, 256, 0, stream>>>(W0, Wth, Wtl, 256);
    gemm_mfma_kernel<false><<<dim3(gx, 2), 256, 0, stream>>>(x, Wth, Wtl, b0, nullptr, nullptr, hA, M, 256);
    spmm_kernel<256><<<spmm_grid, 256, 0, stream>>>(rowptr, ccol, cval, hA, hB, M);

    hipMemsetAsync(sums, 0, 2048, stream);
    bn_stats_kernel<<<256, 256, 0, stream>>>(hB, sums, sumsq, M);
    bn_finalize_kernel<<<1, 256, 0, stream>>>(sums, sumsq, g0, be0, scale, shift, M);

    // --- layer 1 ---
    wsplit_kernel<<<(256 * 256 + 255) / 256, 256, 0, stream>>>(W1, Wth, Wtl, 256);
    gemm_mfma_kernel<true><<<dim3(gx, 2), 256, 0, stream>>>(hB, Wth, Wtl, b1, scale, shift, hA, M, 256);
    spmm_kernel<256><<<spmm_grid, 256, 0, stream>>>(rowptr, ccol, cval, hA, hB, M);

    hipMemsetAsync(sums, 0, 2048, stream);
    bn_stats_kernel<<<256, 256, 0, stream>>>(hB, sums, sumsq, M);
    bn_finalize_kernel<<<1, 256, 0, stream>>>(sums, sumsq, g1, be1, scale, shift, M);

    // --- layer 2 (N=128) ---
    wsplit_kernel<<<(256 * 128 + 255) / 256, 256, 0, stream>>>(W2, Wth, Wtl, 128);
    gemm_mfma_kernel<true><<<dim3(gx, 1), 256, 0, stream>>>(hB, Wth, Wtl, b2, scale, shift, hA, M, 128);
    spmm_kernel<128><<<spmm_grid, 256, 0, stream>>>(rowptr, ccol, cval, hA, out, M);
}

// Round 8
// 1669.149 us; speedup vs baseline: 1.5678x; 1.3938x over previous
//
#include <hip/hip_runtime.h>

// ---------------------------------------------------------------------------
// GCN encoder: 3x { bf16-MFMA GEMM -> SpMM } with BN+ReLU fused into GEMM
// input staging. All intermediate activations stored bf16 (halves gather BW).
// W split hi+lo bf16 (2 MFMA) for near-fp32 weight precision.
// CSR built on-device each launch; edges stored interleaved {col,val} 8B.
// ---------------------------------------------------------------------------

typedef __attribute__((ext_vector_type(8))) short s8b;   // 8 bf16 (4 VGPRs)
typedef __attribute__((ext_vector_type(4))) float f32x4; // MFMA accumulator

__device__ inline unsigned short bf16_rne(float f) {
    unsigned u = __float_as_uint(f);
    return (unsigned short)((u + 0x7fffu + ((u >> 16) & 1u)) >> 16);
}
__device__ inline float bf16_to_f(unsigned short h) {
    return __uint_as_float((unsigned)h << 16);
}

// ---------------------------- CSR build ------------------------------------
__global__ void hist_kernel(const int* __restrict__ row, int* __restrict__ rowptr, int E) {
    int i = blockIdx.x * blockDim.x + threadIdx.x;
    int stride = gridDim.x * blockDim.x;
    for (; i < E; i += stride) atomicAdd(&rowptr[row[i] + 1], 1);
}

__global__ __launch_bounds__(1024) void scan_kernel(int* __restrict__ rowptr,
                                                    int* __restrict__ cursor,
                                                    int n, int N) {
    __shared__ int warp_sums[16];
    __shared__ int s_run;
    int t = threadIdx.x;
    int wid = t >> 6, lane = t & 63;
    if (t == 0) s_run = 0;
    __syncthreads();
    const int CHUNK = 1024 * 8;
    for (int base = 0; base < n; base += CHUNK) {
        int v[8];
        int local = 0;
        int i0 = base + t * 8;
#pragma unroll
        for (int j = 0; j < 8; ++j) {
            int idx = i0 + j;
            v[j] = (idx < n) ? rowptr[idx] : 0;
            local += v[j];
        }
        int x = local;
#pragma unroll
        for (int off = 1; off < 64; off <<= 1) {
            int y = __shfl_up(x, off);
            if (lane >= off) x += y;
        }
        if (lane == 63) warp_sums[wid] = x;
        __syncthreads();
        if (wid == 0) {
            int w = (lane < 16) ? warp_sums[lane] : 0;
#pragma unroll
            for (int off = 1; off < 16; off <<= 1) {
                int y = __shfl_up(w, off);
                if (lane >= off) w += y;
            }
            if (lane < 16) warp_sums[lane] = w;
        }
        __syncthreads();
        int wave_off = (wid > 0) ? warp_sums[wid - 1] : 0;
        int chunk_total = warp_sums[15];
        int acc = (x - local) + wave_off + s_run;
#pragma unroll
        for (int j = 0; j < 8; ++j) {
            int idx = i0 + j;
            acc += v[j];
            if (idx < n) {
                rowptr[idx] = acc;
                if (idx < N) cursor[idx] = acc;
            }
        }
        __syncthreads();
        if (t == 0) s_run += chunk_total;
        __syncthreads();
    }
}

__global__ void scatter_kernel(const int* __restrict__ row, const int* __restrict__ col,
                               const float* __restrict__ vals, int* __restrict__ cursor,
                               int2* __restrict__ edges, int E) {
    int i = blockIdx.x * blockDim.x + threadIdx.x;
    int stride = gridDim.x * blockDim.x;
    for (; i < E; i += stride) {
        int r = row[i];
        int p = atomicAdd(&cursor[r], 1);
        edges[p] = make_int2(col[i], __float_as_int(vals[i]));
    }
}

// ------------------- W preprocessing: transpose + bf16 split ---------------
__global__ void wsplit_kernel(const float* __restrict__ W, short* __restrict__ Wt_hi,
                              short* __restrict__ Wt_lo, int N) {
    const int K = 256;
    int i = blockIdx.x * blockDim.x + threadIdx.x;
    if (i >= K * N) return;
    int k = i / N, n = i % N;
    float f = W[i];
    unsigned short h = bf16_rne(f);
    unsigned short l = bf16_rne(f - bf16_to_f(h));
    Wt_hi[(size_t)n * K + k] = (short)h;
    Wt_lo[(size_t)n * K + k] = (short)l;
}

// --------------------------- MFMA GEMM -------------------------------------
// C_bf16[M,N] = act(A)[M,256] @ W[256,N] + bias.
// FIRST: A fp32, no BN.  else: A bf16, BN affine + ReLU during staging.
// Block 128x128, 4 waves 2x2, wave = 64x64 = 4x4 frags of 16x16x32.
template <bool FIRST>
__global__ __launch_bounds__(256) void gemm_mfma_kernel(
    const void* __restrict__ Aptr, const short* __restrict__ Wth,
    const short* __restrict__ Wtl, const float* __restrict__ bias,
    const float* __restrict__ scale, const float* __restrict__ shift,
    unsigned short* __restrict__ C, int M, int N) {
    const int K = 256;
    const int LDT = 40;  // padded k-stride (bf16): 80B row stride spreads banks
    __shared__ short Ah[128 * LDT], Bh[128 * LDT], Bl[128 * LDT];

    int t = threadIdx.x;
    int wave = t >> 6, lane = t & 63;
    int wm = wave >> 1, wn = wave & 1;
    int row0 = blockIdx.x * 128;
    int n0 = blockIdx.y * 128;

    int srow = t >> 1;       // 0..127
    int skh = (t & 1) * 16;  // 0 or 16 within the 32-wide K-step

    int lr = lane & 15;
    int lg = (lane >> 4) * 8;

    f32x4 acc[4][4];
#pragma unroll
    for (int i = 0; i < 4; ++i)
#pragma unroll
        for (int j = 0; j < 4; ++j) acc[i][j] = (f32x4){0.f, 0.f, 0.f, 0.f};

    for (int k0 = 0; k0 < K; k0 += 32) {
        // ---- stage A ----
        float va[16];
        int gr = row0 + srow;
        if constexpr (FIRST) {
            if (gr < M) {
                const float4* ap = (const float4*)((const float*)Aptr + (size_t)gr * K + k0 + skh);
#pragma unroll
                for (int q = 0; q < 4; ++q) {
                    float4 v = ap[q];
                    va[4 * q + 0] = v.x; va[4 * q + 1] = v.y;
                    va[4 * q + 2] = v.z; va[4 * q + 3] = v.w;
                }
            } else {
#pragma unroll
                for (int q = 0; q < 16; ++q) va[q] = 0.f;
            }
        } else {
            if (gr < M) {
                const s8b* ap = (const s8b*)((const unsigned short*)Aptr + (size_t)gr * K + k0 + skh);
                s8b r0 = ap[0], r1 = ap[1];
#pragma unroll
                for (int q = 0; q < 8; ++q) {
                    va[q] = bf16_to_f((unsigned short)r0[q]);
                    va[8 + q] = bf16_to_f((unsigned short)r1[q]);
                }
            } else {
#pragma unroll
                for (int q = 0; q < 16; ++q) va[q] = 0.f;
            }
            // BN affine + ReLU
#pragma unroll
            for (int q = 0; q < 4; ++q) {
                float4 sc = *(const float4*)(scale + k0 + skh + 4 * q);
                float4 sh = *(const float4*)(shift + k0 + skh + 4 * q);
                va[4 * q + 0] = fmaxf(va[4 * q + 0] * sc.x + sh.x, 0.f);
                va[4 * q + 1] = fmaxf(va[4 * q + 1] * sc.y + sh.y, 0.f);
                va[4 * q + 2] = fmaxf(va[4 * q + 2] * sc.z + sh.z, 0.f);
                va[4 * q + 3] = fmaxf(va[4 * q + 3] * sc.w + sh.w, 0.f);
            }
        }
        s8b vh0, vh1;
#pragma unroll
        for (int q = 0; q < 8; ++q) {
            vh0[q] = (short)bf16_rne(va[q]);
            vh1[q] = (short)bf16_rne(va[8 + q]);
        }
        *(s8b*)&Ah[srow * LDT + skh]     = vh0;
        *(s8b*)&Ah[srow * LDT + skh + 8] = vh1;

        // ---- stage B (pre-split W^T) ----
        int gn = n0 + srow;
        const s8b* wph = (const s8b*)(Wth + (size_t)gn * K + k0 + skh);
        const s8b* wpl = (const s8b*)(Wtl + (size_t)gn * K + k0 + skh);
        s8b wh0 = wph[0], wh1 = wph[1];
        s8b wl0 = wpl[0], wl1 = wpl[1];
        *(s8b*)&Bh[srow * LDT + skh]     = wh0;
        *(s8b*)&Bh[srow * LDT + skh + 8] = wh1;
        *(s8b*)&Bl[srow * LDT + skh]     = wl0;
        *(s8b*)&Bl[srow * LDT + skh + 8] = wl1;
        __syncthreads();

        // ---- MFMA ----
        s8b a[4], bh[4], bl[4];
#pragma unroll
        for (int i = 0; i < 4; ++i)
            a[i] = *(const s8b*)&Ah[(wm * 64 + i * 16 + lr) * LDT + lg];
#pragma unroll
        for (int j = 0; j < 4; ++j) {
            int c = (wn * 64 + j * 16 + lr) * LDT + lg;
            bh[j] = *(const s8b*)&Bh[c];
            bl[j] = *(const s8b*)&Bl[c];
        }
#pragma unroll
        for (int i = 0; i < 4; ++i)
#pragma unroll
            for (int j = 0; j < 4; ++j) {
                acc[i][j] = __builtin_amdgcn_mfma_f32_16x16x32_bf16(a[i], bh[j], acc[i][j], 0, 0, 0);
                acc[i][j] = __builtin_amdgcn_mfma_f32_16x16x32_bf16(a[i], bl[j], acc[i][j], 0, 0, 0);
            }
        __syncthreads();
    }

    // ---- epilogue: C/D layout col=lane&15, row=4*(lane>>4)+reg ----
    int lq = lane >> 4;
#pragma unroll
    for (int j = 0; j < 4; ++j) {
        int colg = n0 + wn * 64 + j * 16 + lr;
        float bb = bias[colg];
#pragma unroll
        for (int i = 0; i < 4; ++i) {
#pragma unroll
            for (int r = 0; r < 4; ++r) {
                int rowg = row0 + wm * 64 + i * 16 + lq * 4 + r;
                if (rowg < M) C[(size_t)rowg * N + colg] = bf16_rne(acc[i][j][r] + bb);
            }
        }
    }
}

// ------------------------------- SpMM --------------------------------------
// One wave per row. H is bf16. Unroll 4 edges -> 4 outstanding gathers.
template <int F, bool OUT_BF16>
__global__ __launch_bounds__(256) void spmm_kernel(const int* __restrict__ rowptr,
                                                   const int2* __restrict__ edges,
                                                   const unsigned short* __restrict__ H,
                                                   void* __restrict__ out, int M) {
    int wid = threadIdx.x >> 6;
    int lane = threadIdx.x & 63;
    int r = blockIdx.x * 4 + wid;
    if (r >= M) return;
    int e0 = rowptr[r], e1 = rowptr[r + 1];
    if constexpr (F == 256) {
        const ushort4* Hv = (const ushort4*)H;  // row = 64 x ushort4
        float4 acc = {0.f, 0.f, 0.f, 0.f};
        int e = e0;
        for (; e + 4 <= e1; e += 4) {
            int2 E0 = edges[e], E1 = edges[e + 1], E2 = edges[e + 2], E3 = edges[e + 3];
            ushort4 h0 = Hv[(size_t)E0.x * 64 + lane];
            ushort4 h1 = Hv[(size_t)E1.x * 64 + lane];
            ushort4 h2 = Hv[(size_t)E2.x * 64 + lane];
            ushort4 h3 = Hv[(size_t)E3.x * 64 + lane];
            float v0 = __int_as_float(E0.y), v1 = __int_as_float(E1.y);
            float v2 = __int_as_float(E2.y), v3 = __int_as_float(E3.y);
            acc.x += v0 * bf16_to_f(h0.x); acc.y += v0 * bf16_to_f(h0.y);
            acc.z += v0 * bf16_to_f(h0.z); acc.w += v0 * bf16_to_f(h0.w);
            acc.x += v1 * bf16_to_f(h1.x); acc.y += v1 * bf16_to_f(h1.y);
            acc.z += v1 * bf16_to_f(h1.z); acc.w += v1 * bf16_to_f(h1.w);
            acc.x += v2 * bf16_to_f(h2.x); acc.y += v2 * bf16_to_f(h2.y);
            acc.z += v2 * bf16_to_f(h2.z); acc.w += v2 * bf16_to_f(h2.w);
            acc.x += v3 * bf16_to_f(h3.x); acc.y += v3 * bf16_to_f(h3.y);
            acc.z += v3 * bf16_to_f(h3.z); acc.w += v3 * bf16_to_f(h3.w);
        }
        for (; e < e1; ++e) {
            int2 E0 = edges[e];
            ushort4 h0 = Hv[(size_t)E0.x * 64 + lane];
            float v0 = __int_as_float(E0.y);
            acc.x += v0 * bf16_to_f(h0.x); acc.y += v0 * bf16_to_f(h0.y);
            acc.z += v0 * bf16_to_f(h0.z); acc.w += v0 * bf16_to_f(h0.w);
        }
        if constexpr (OUT_BF16) {
            ushort4 o;
            o.x = bf16_rne(acc.x); o.y = bf16_rne(acc.y);
            o.z = bf16_rne(acc.z); o.w = bf16_rne(acc.w);
            ((ushort4*)out)[(size_t)r * 64 + lane] = o;
        } else {
            ((float4*)out)[(size_t)r * 64 + lane] = acc;
        }
    } else {  // F == 128
        const ushort2* Hv = (const ushort2*)H;  // row = 64 x ushort2
        float2 acc = {0.f, 0.f};
        int e = e0;
        for (; e + 4 <= e1; e += 4) {
            int2 E0 = edges[e], E1 = edges[e + 1], E2 = edges[e + 2], E3 = edges[e + 3];
            ushort2 h0 = Hv[(size_t)E0.x * 64 + lane];
            ushort2 h1 = Hv[(size_t)E1.x * 64 + lane];
            ushort2 h2 = Hv[(size_t)E2.x * 64 + lane];
            ushort2 h3 = Hv[(size_t)E3.x * 64 + lane];
            float v0 = __int_as_float(E0.y), v1 = __int_as_float(E1.y);
            float v2 = __int_as_float(E2.y), v3 = __int_as_float(E3.y);
            acc.x += v0 * bf16_to_f(h0.x); acc.y += v0 * bf16_to_f(h0.y);
            acc.x += v1 * bf16_to_f(h1.x); acc.y += v1 * bf16_to_f(h1.y);
            acc.x += v2 * bf16_to_f(h2.x); acc.y += v2 * bf16_to_f(h2.y);
            acc.x += v3 * bf16_to_f(h3.x); acc.y += v3 * bf16_to_f(h3.y);
        }
        for (; e < e1; ++e) {
            int2 E0 = edges[e];
            ushort2 h0 = Hv[(size_t)E0.x * 64 + lane];
            float v0 = __int_as_float(E0.y);
            acc.x += v0 * bf16_to_f(h0.x); acc.y += v0 * bf16_to_f(h0.y);
        }
        if constexpr (OUT_BF16) {
            ushort2 o;
            o.x = bf16_rne(acc.x); o.y = bf16_rne(acc.y);
            ((ushort2*)out)[(size_t)r * 64 + lane] = o;
        } else {
            ((float2*)out)[(size_t)r * 64 + lane] = acc;
        }
    }
}

// ------------------------------- BN ----------------------------------------
__global__ __launch_bounds__(256) void bn_stats_kernel(const unsigned short* __restrict__ H,
                                                       float* __restrict__ sums,
                                                       float* __restrict__ sumsq, int M) {
    int c = threadIdx.x;
    int nb = gridDim.x;
    int rows_per = (M + nb - 1) / nb;
    int r0 = blockIdx.x * rows_per;
    int r1 = min(M, r0 + rows_per);
    float s = 0.f, q = 0.f;
    for (int r = r0; r < r1; ++r) {
        float v = bf16_to_f(H[(size_t)r * 256 + c]);
        s += v;
        q += v * v;
    }
    atomicAdd(&sums[c], s);
    atomicAdd(&sumsq[c], q);
}

__global__ void bn_finalize_kernel(const float* __restrict__ sums, const float* __restrict__ sumsq,
                                   const float* __restrict__ g, const float* __restrict__ be,
                                   float* __restrict__ scale, float* __restrict__ shift, int M) {
    int c = threadIdx.x;
    float mean = sums[c] / (float)M;
    float var = sumsq[c] / (float)M - mean * mean;
    float inv = rsqrtf(var + 1e-5f);
    float s = g[c] * inv;
    scale[c] = s;
    shift[c] = be[c] - mean * s;
}

extern "C" void kernel_launch(void* const* d_in, const int* in_sizes, int n_in,
                              void* d_out, int out_size, void* d_ws, size_t ws_size,
                              hipStream_t stream) {
    const float* x   = (const float*)d_in[0];
    const float* vals= (const float*)d_in[1];
    const float* W0  = (const float*)d_in[2];
    const float* b0  = (const float*)d_in[3];
    const float* g0  = (const float*)d_in[4];
    const float* be0 = (const float*)d_in[5];
    const float* W1  = (const float*)d_in[6];
    const float* b1  = (const float*)d_in[7];
    const float* g1  = (const float*)d_in[8];
    const float* be1 = (const float*)d_in[9];
    const float* W2  = (const float*)d_in[10];
    const float* b2  = (const float*)d_in[11];
    const int* row   = (const int*)d_in[12];
    const int* col   = (const int*)d_in[13];
    const int E = in_sizes[1];
    const int M = in_sizes[0] / 256;
    float* out = (float*)d_out;

    char* ws = (char*)d_ws;
    size_t off = 0;
    auto alloc = [&](size_t bytes) -> void* {
        void* p = ws + off;
        off += (bytes + 255) & ~(size_t)255;
        return p;
    };
    unsigned short* hA = (unsigned short*)alloc((size_t)M * 256 * 2);  // gemm out (bf16)
    unsigned short* hB = (unsigned short*)alloc((size_t)M * 256 * 2);  // spmm out (bf16)
    int2*  edges = (int2*)alloc((size_t)E * 8);
    int*   rowptr= (int*)alloc((size_t)(M + 1) * 4);
    int*   cursor= (int*)alloc((size_t)M * 4);
    float* sums  = (float*)alloc(256 * 4);
    float* sumsq = (float*)alloc(256 * 4);
    float* scale = (float*)alloc(256 * 4);
    float* shift = (float*)alloc(256 * 4);
    short* Wth   = (short*)alloc((size_t)256 * 256 * 2);
    short* Wtl   = (short*)alloc((size_t)256 * 256 * 2);

    // --- CSR build ---
    hipMemsetAsync(rowptr, 0, (size_t)(M + 1) * 4, stream);
    hist_kernel<<<2048, 256, 0, stream>>>(row, rowptr, E);
    scan_kernel<<<1, 1024, 0, stream>>>(rowptr, cursor, M + 1, M);
    scatter_kernel<<<2048, 256, 0, stream>>>(row, col, vals, cursor, edges, E);

    int gx = (M + 127) / 128;
    int spmm_grid = (M + 3) / 4;

    // --- layer 0 ---
    wsplit_kernel<<<(256 * 256 + 255) / 256, 256, 0, stream>>>(W0, Wth, Wtl, 256);
    gemm_mfma_kernel<true><<<dim3(gx, 2), 256, 0, stream>>>(x, Wth, Wtl, b0, nullptr, nullptr, hA, M, 256);
    spmm_kernel<256, true><<<spmm_grid, 256, 0, stream>>>(rowptr, edges, hA, hB, M);

    hipMemsetAsync(sums, 0, 2048, stream);
    bn_stats_kernel<<<256, 256, 0, stream>>>(hB, sums, sumsq, M);
    bn_finalize_kernel<<<1, 256, 0, stream>>>(sums, sumsq, g0, be0, scale, shift, M);

    // --- layer 1 ---
    wsplit_kernel<<<(256 * 256 + 255) / 256, 256, 0, stream>>>(W1, Wth, Wtl, 256);
    gemm_mfma_kernel<false><<<dim3(gx, 2), 256, 0, stream>>>(hB, Wth, Wtl, b1, scale, shift, hA, M, 256);
    spmm_kernel<256, true><<<spmm_grid, 256, 0, stream>>>(rowptr, edges, hA, hB, M);

    hipMemsetAsync(sums, 0, 2048, stream);
    bn_stats_kernel<<<256, 256, 0, stream>>>(hB, sums, sumsq, M);
    bn_finalize_kernel<<<1, 256, 0, stream>>>(sums, sumsq, g1, be1, scale, shift, M);

    // --- layer 2 (N=128) ---
    wsplit_kernel<<<(256 * 128 + 255) / 256, 256, 0, stream>>>(W2, Wth, Wtl, 128);
    gemm_mfma_kernel<false><<<dim3(gx, 1), 256, 0, stream>>>(hB, Wth, Wtl, b2, scale, shift, hA, M, 128);
    spmm_kernel<128, false><<<spmm_grid, 256, 0, stream>>>(rowptr, edges, hA, out, M);
}

// Round 9
// 1321.234 us; speedup vs baseline: 1.9806x; 1.2633x over previous
//
#include <hip/hip_runtime.h>

// ---------------------------------------------------------------------------
// GCN encoder: 3x { bf16-MFMA GEMM -> SpMM }, BN+ReLU fused into GEMM staging.
// CSR built per-launch via atomic-free 2-pass LDS counting sort:
//   A) per-block LDS histogram of buckets (row>>9)        -> hist2d[b][blk]
//   B) single-block exclusive scan of hist2d              -> base2d
//   C) bucket scatter (LDS cursors, packed {rl,col,val})  -> ebuf (bucket-contig)
//   D) per-bucket LDS sort by row, writes rowptr + edges  (L2-local region)
// ---------------------------------------------------------------------------

typedef __attribute__((ext_vector_type(8))) short s8b;   // 8 bf16 (4 VGPRs)
typedef __attribute__((ext_vector_type(4))) float f32x4; // MFMA accumulator

__device__ inline unsigned short bf16_rne(float f) {
    unsigned u = __float_as_uint(f);
    return (unsigned short)((u + 0x7fffu + ((u >> 16) & 1u)) >> 16);
}
__device__ inline float bf16_to_f(unsigned short h) {
    return __uint_as_float((unsigned)h << 16);
}

#define NBLK_AC 256  // blocks for passes A and C (must match between them)

// ---- pass A: per-block bucket histogram (bucket = row>>9, NB<=256) --------
__global__ __launch_bounds__(256) void bucket_hist(const int* __restrict__ row,
                                                   int* __restrict__ hist2d,
                                                   int E, int NB) {
    __shared__ int cnt[256];
    int t = threadIdx.x, blk = blockIdx.x;
    cnt[t] = 0;
    __syncthreads();
    int chunk = (E + gridDim.x - 1) / gridDim.x;
    int e0 = blk * chunk, e1 = min(E, e0 + chunk);
    for (int e = e0 + t; e < e1; e += 256) atomicAdd(&cnt[((unsigned)row[e]) >> 9], 1);
    __syncthreads();
    if (t < NB) hist2d[t * NBLK_AC + blk] = cnt[t];
}

// ---- pass B: single-block exclusive scan over L = NB*NBLK_AC ints ---------
__global__ __launch_bounds__(1024) void excl_scan(const int* __restrict__ in,
                                                  int* __restrict__ out, int L) {
    __shared__ int wsum[16];
    __shared__ int s_run;
    int t = threadIdx.x;
    int wid = t >> 6, lane = t & 63;
    if (t == 0) s_run = 0;
    __syncthreads();
    const int CHUNK = 1024 * 8;
    for (int base = 0; base < L; base += CHUNK) {
        int v[8];
        int local = 0;
        int i0 = base + t * 8;
#pragma unroll
        for (int j = 0; j < 8; ++j) {
            int idx = i0 + j;
            v[j] = (idx < L) ? in[idx] : 0;
            local += v[j];
        }
        int x = local;
#pragma unroll
        for (int off = 1; off < 64; off <<= 1) {
            int y = __shfl_up(x, off);
            if (lane >= off) x += y;
        }
        if (lane == 63) wsum[wid] = x;
        __syncthreads();
        if (wid == 0) {
            int w = (lane < 16) ? wsum[lane] : 0;
#pragma unroll
            for (int off = 1; off < 16; off <<= 1) {
                int y = __shfl_up(w, off);
                if (lane >= off) w += y;
            }
            if (lane < 16) wsum[lane] = w;
        }
        __syncthreads();
        int wave_off = (wid > 0) ? wsum[wid - 1] : 0;
        int chunk_total = wsum[15];
        int acc = (x - local) + wave_off + s_run;  // exclusive prefix
#pragma unroll
        for (int j = 0; j < 8; ++j) {
            int idx = i0 + j;
            if (idx < L) out[idx] = acc;
            acc += v[j];
        }
        __syncthreads();
        if (t == 0) s_run += chunk_total;
        __syncthreads();
    }
}

// ---- pass C: scatter into bucket-contiguous ebuf, packed {rl<<23|col, val} -
__global__ __launch_bounds__(256) void bucket_scatter(const int* __restrict__ row,
                                                      const int* __restrict__ col,
                                                      const float* __restrict__ vals,
                                                      const int* __restrict__ base2d,
                                                      int2* __restrict__ ebuf,
                                                      int E, int NB) {
    __shared__ int cur[256];
    int t = threadIdx.x, blk = blockIdx.x;
    if (t < NB) cur[t] = base2d[t * NBLK_AC + blk];
    __syncthreads();
    int chunk = (E + gridDim.x - 1) / gridDim.x;
    int e0 = blk * chunk, e1 = min(E, e0 + chunk);
    for (int e = e0 + t; e < e1; e += 256) {
        int r = row[e];
        int b = ((unsigned)r) >> 9;
        int p = atomicAdd(&cur[b], 1);  // LDS atomic only
        ebuf[p] = make_int2(((r & 511) << 23) | col[e], __float_as_int(vals[e]));
    }
}

// ---- pass D: per-bucket sort by local row; writes rowptr + final edges ----
__global__ __launch_bounds__(256) void bucket_sort(const int2* __restrict__ ebuf,
                                                   const int* __restrict__ base2d,
                                                   int2* __restrict__ edges,
                                                   int* __restrict__ rowptr,
                                                   int E, int M, int NB) {
    __shared__ int cnt[512];
    __shared__ int excl[512];
    int b = blockIdx.x, t = threadIdx.x;
    int bstart = base2d[b * NBLK_AC];
    int bend = (b + 1 < NB) ? base2d[(b + 1) * NBLK_AC] : E;
    cnt[t] = 0;
    cnt[t + 256] = 0;
    __syncthreads();
    for (int i = bstart + t; i < bend; i += 256)
        atomicAdd(&cnt[((unsigned)ebuf[i].x) >> 23], 1);
    __syncthreads();
    if (t == 0) {  // serial 512-scan in LDS; blocks run concurrently
        int a = 0;
#pragma unroll 8
        for (int i = 0; i < 512; ++i) { excl[i] = a; a += cnt[i]; }
    }
    __syncthreads();
    for (int rl = t; rl < 512; rl += 256) {
        int r0 = b * 512 + rl;
        if (r0 < M) rowptr[r0] = bstart + excl[rl];
    }
    if (b == 0 && t == 0) rowptr[M] = E;
    cnt[t] = excl[t];
    cnt[t + 256] = excl[t + 256];
    __syncthreads();
    for (int i = bstart + t; i < bend; i += 256) {
        int2 eb = ebuf[i];
        int rl = ((unsigned)eb.x) >> 23;
        int p = bstart + atomicAdd(&cnt[rl], 1);  // LDS atomic only
        edges[p] = make_int2(eb.x & 0x7FFFFF, eb.y);
    }
}

// ------------------- W preprocessing: transpose + bf16 split ---------------
__global__ void wsplit_kernel(const float* __restrict__ W, short* __restrict__ Wt_hi,
                              short* __restrict__ Wt_lo, int N) {
    const int K = 256;
    int i = blockIdx.x * blockDim.x + threadIdx.x;
    if (i >= K * N) return;
    int k = i / N, n = i % N;
    float f = W[i];
    unsigned short h = bf16_rne(f);
    unsigned short l = bf16_rne(f - bf16_to_f(h));
    Wt_hi[(size_t)n * K + k] = (short)h;
    Wt_lo[(size_t)n * K + k] = (short)l;
}

// --------------------------- MFMA GEMM -------------------------------------
template <bool FIRST>
__global__ __launch_bounds__(256) void gemm_mfma_kernel(
    const void* __restrict__ Aptr, const short* __restrict__ Wth,
    const short* __restrict__ Wtl, const float* __restrict__ bias,
    const float* __restrict__ scale, const float* __restrict__ shift,
    unsigned short* __restrict__ C, int M, int N) {
    const int K = 256;
    const int LDT = 40;  // padded k-stride (bf16): 80B row stride spreads banks
    __shared__ short Ah[128 * LDT], Bh[128 * LDT], Bl[128 * LDT];

    int t = threadIdx.x;
    int wave = t >> 6, lane = t & 63;
    int wm = wave >> 1, wn = wave & 1;
    int row0 = blockIdx.x * 128;
    int n0 = blockIdx.y * 128;

    int srow = t >> 1;
    int skh = (t & 1) * 16;

    int lr = lane & 15;
    int lg = (lane >> 4) * 8;

    f32x4 acc[4][4];
#pragma unroll
    for (int i = 0; i < 4; ++i)
#pragma unroll
        for (int j = 0; j < 4; ++j) acc[i][j] = (f32x4){0.f, 0.f, 0.f, 0.f};

    for (int k0 = 0; k0 < K; k0 += 32) {
        float va[16];
        int gr = row0 + srow;
        if constexpr (FIRST) {
            if (gr < M) {
                const float4* ap = (const float4*)((const float*)Aptr + (size_t)gr * K + k0 + skh);
#pragma unroll
                for (int q = 0; q < 4; ++q) {
                    float4 v = ap[q];
                    va[4 * q + 0] = v.x; va[4 * q + 1] = v.y;
                    va[4 * q + 2] = v.z; va[4 * q + 3] = v.w;
                }
            } else {
#pragma unroll
                for (int q = 0; q < 16; ++q) va[q] = 0.f;
            }
        } else {
            if (gr < M) {
                const s8b* ap = (const s8b*)((const unsigned short*)Aptr + (size_t)gr * K + k0 + skh);
                s8b r0 = ap[0], r1 = ap[1];
#pragma unroll
                for (int q = 0; q < 8; ++q) {
                    va[q] = bf16_to_f((unsigned short)r0[q]);
                    va[8 + q] = bf16_to_f((unsigned short)r1[q]);
                }
            } else {
#pragma unroll
                for (int q = 0; q < 16; ++q) va[q] = 0.f;
            }
#pragma unroll
            for (int q = 0; q < 4; ++q) {
                float4 sc = *(const float4*)(scale + k0 + skh + 4 * q);
                float4 sh = *(const float4*)(shift + k0 + skh + 4 * q);
                va[4 * q + 0] = fmaxf(va[4 * q + 0] * sc.x + sh.x, 0.f);
                va[4 * q + 1] = fmaxf(va[4 * q + 1] * sc.y + sh.y, 0.f);
                va[4 * q + 2] = fmaxf(va[4 * q + 2] * sc.z + sh.z, 0.f);
                va[4 * q + 3] = fmaxf(va[4 * q + 3] * sc.w + sh.w, 0.f);
            }
        }
        s8b vh0, vh1;
#pragma unroll
        for (int q = 0; q < 8; ++q) {
            vh0[q] = (short)bf16_rne(va[q]);
            vh1[q] = (short)bf16_rne(va[8 + q]);
        }
        *(s8b*)&Ah[srow * LDT + skh]     = vh0;
        *(s8b*)&Ah[srow * LDT + skh + 8] = vh1;

        int gn = n0 + srow;
        const s8b* wph = (const s8b*)(Wth + (size_t)gn * K + k0 + skh);
        const s8b* wpl = (const s8b*)(Wtl + (size_t)gn * K + k0 + skh);
        s8b wh0 = wph[0], wh1 = wph[1];
        s8b wl0 = wpl[0], wl1 = wpl[1];
        *(s8b*)&Bh[srow * LDT + skh]     = wh0;
        *(s8b*)&Bh[srow * LDT + skh + 8] = wh1;
        *(s8b*)&Bl[srow * LDT + skh]     = wl0;
        *(s8b*)&Bl[srow * LDT + skh + 8] = wl1;
        __syncthreads();

        s8b a[4], bh[4], bl[4];
#pragma unroll
        for (int i = 0; i < 4; ++i)
            a[i] = *(const s8b*)&Ah[(wm * 64 + i * 16 + lr) * LDT + lg];
#pragma unroll
        for (int j = 0; j < 4; ++j) {
            int c = (wn * 64 + j * 16 + lr) * LDT + lg;
            bh[j] = *(const s8b*)&Bh[c];
            bl[j] = *(const s8b*)&Bl[c];
        }
#pragma unroll
        for (int i = 0; i < 4; ++i)
#pragma unroll
            for (int j = 0; j < 4; ++j) {
                acc[i][j] = __builtin_amdgcn_mfma_f32_16x16x32_bf16(a[i], bh[j], acc[i][j], 0, 0, 0);
                acc[i][j] = __builtin_amdgcn_mfma_f32_16x16x32_bf16(a[i], bl[j], acc[i][j], 0, 0, 0);
            }
        __syncthreads();
    }

    int lq = lane >> 4;
#pragma unroll
    for (int j = 0; j < 4; ++j) {
        int colg = n0 + wn * 64 + j * 16 + lr;
        float bb = bias[colg];
#pragma unroll
        for (int i = 0; i < 4; ++i) {
#pragma unroll
            for (int r = 0; r < 4; ++r) {
                int rowg = row0 + wm * 64 + i * 16 + lq * 4 + r;
                if (rowg < M) C[(size_t)rowg * N + colg] = bf16_rne(acc[i][j][r] + bb);
            }
        }
    }
}

// ------------------------------- SpMM --------------------------------------
template <int F, bool OUT_BF16>
__global__ __launch_bounds__(256) void spmm_kernel(const int* __restrict__ rowptr,
                                                   const int2* __restrict__ edges,
                                                   const unsigned short* __restrict__ H,
                                                   void* __restrict__ out, int M) {
    int wid = threadIdx.x >> 6;
    int lane = threadIdx.x & 63;
    int r = blockIdx.x * 4 + wid;
    if (r >= M) return;
    int e0 = rowptr[r], e1 = rowptr[r + 1];
    if constexpr (F == 256) {
        const ushort4* Hv = (const ushort4*)H;
        float4 acc = {0.f, 0.f, 0.f, 0.f};
        int e = e0;
        for (; e + 4 <= e1; e += 4) {
            int2 E0 = edges[e], E1 = edges[e + 1], E2 = edges[e + 2], E3 = edges[e + 3];
            ushort4 h0 = Hv[(size_t)E0.x * 64 + lane];
            ushort4 h1 = Hv[(size_t)E1.x * 64 + lane];
            ushort4 h2 = Hv[(size_t)E2.x * 64 + lane];
            ushort4 h3 = Hv[(size_t)E3.x * 64 + lane];
            float v0 = __int_as_float(E0.y), v1 = __int_as_float(E1.y);
            float v2 = __int_as_float(E2.y), v3 = __int_as_float(E3.y);
            acc.x += v0 * bf16_to_f(h0.x); acc.y += v0 * bf16_to_f(h0.y);
            acc.z += v0 * bf16_to_f(h0.z); acc.w += v0 * bf16_to_f(h0.w);
            acc.x += v1 * bf16_to_f(h1.x); acc.y += v1 * bf16_to_f(h1.y);
            acc.z += v1 * bf16_to_f(h1.z); acc.w += v1 * bf16_to_f(h1.w);
            acc.x += v2 * bf16_to_f(h2.x); acc.y += v2 * bf16_to_f(h2.y);
            acc.z += v2 * bf16_to_f(h2.z); acc.w += v2 * bf16_to_f(h2.w);
            acc.x += v3 * bf16_to_f(h3.x); acc.y += v3 * bf16_to_f(h3.y);
            acc.z += v3 * bf16_to_f(h3.z); acc.w += v3 * bf16_to_f(h3.w);
        }
        for (; e < e1; ++e) {
            int2 E0 = edges[e];
            ushort4 h0 = Hv[(size_t)E0.x * 64 + lane];
            float v0 = __int_as_float(E0.y);
            acc.x += v0 * bf16_to_f(h0.x); acc.y += v0 * bf16_to_f(h0.y);
            acc.z += v0 * bf16_to_f(h0.z); acc.w += v0 * bf16_to_f(h0.w);
        }
        if constexpr (OUT_BF16) {
            ushort4 o;
            o.x = bf16_rne(acc.x); o.y = bf16_rne(acc.y);
            o.z = bf16_rne(acc.z); o.w = bf16_rne(acc.w);
            ((ushort4*)out)[(size_t)r * 64 + lane] = o;
        } else {
            ((float4*)out)[(size_t)r * 64 + lane] = acc;
        }
    } else {  // F == 128
        const ushort2* Hv = (const ushort2*)H;
        float2 acc = {0.f, 0.f};
        int e = e0;
        for (; e + 4 <= e1; e += 4) {
            int2 E0 = edges[e], E1 = edges[e + 1], E2 = edges[e + 2], E3 = edges[e + 3];
            ushort2 h0 = Hv[(size_t)E0.x * 64 + lane];
            ushort2 h1 = Hv[(size_t)E1.x * 64 + lane];
            ushort2 h2 = Hv[(size_t)E2.x * 64 + lane];
            ushort2 h3 = Hv[(size_t)E3.x * 64 + lane];
            float v0 = __int_as_float(E0.y), v1 = __int_as_float(E1.y);
            float v2 = __int_as_float(E2.y), v3 = __int_as_float(E3.y);
            acc.x += v0 * bf16_to_f(h0.x); acc.y += v0 * bf16_to_f(h0.y);
            acc.x += v1 * bf16_to_f(h1.x); acc.y += v1 * bf16_to_f(h1.y);
            acc.x += v2 * bf16_to_f(h2.x); acc.y += v2 * bf16_to_f(h2.y);
            acc.x += v3 * bf16_to_f(h3.x); acc.y += v3 * bf16_to_f(h3.y);
        }
        for (; e < e1; ++e) {
            int2 E0 = edges[e];
            ushort2 h0 = Hv[(size_t)E0.x * 64 + lane];
            float v0 = __int_as_float(E0.y);
            acc.x += v0 * bf16_to_f(h0.x); acc.y += v0 * bf16_to_f(h0.y);
        }
        if constexpr (OUT_BF16) {
            ushort2 o;
            o.x = bf16_rne(acc.x); o.y = bf16_rne(acc.y);
            ((ushort2*)out)[(size_t)r * 64 + lane] = o;
        } else {
            ((float2*)out)[(size_t)r * 64 + lane] = acc;
        }
    }
}

// ------------------------------- BN ----------------------------------------
__global__ __launch_bounds__(256) void bn_stats_kernel(const unsigned short* __restrict__ H,
                                                       float* __restrict__ sums,
                                                       float* __restrict__ sumsq, int M) {
    int c = threadIdx.x;
    int nb = gridDim.x;
    int rows_per = (M + nb - 1) / nb;
    int r0 = blockIdx.x * rows_per;
    int r1 = min(M, r0 + rows_per);
    float s = 0.f, q = 0.f;
    for (int r = r0; r < r1; ++r) {
        float v = bf16_to_f(H[(size_t)r * 256 + c]);
        s += v;
        q += v * v;
    }
    atomicAdd(&sums[c], s);
    atomicAdd(&sumsq[c], q);
}

__global__ void bn_finalize_kernel(const float* __restrict__ sums, const float* __restrict__ sumsq,
                                   const float* __restrict__ g, const float* __restrict__ be,
                                   float* __restrict__ scale, float* __restrict__ shift, int M) {
    int c = threadIdx.x;
    float mean = sums[c] / (float)M;
    float var = sumsq[c] / (float)M - mean * mean;
    float inv = rsqrtf(var + 1e-5f);
    float s = g[c] * inv;
    scale[c] = s;
    shift[c] = be[c] - mean * s;
}

extern "C" void kernel_launch(void* const* d_in, const int* in_sizes, int n_in,
                              void* d_out, int out_size, void* d_ws, size_t ws_size,
                              hipStream_t stream) {
    const float* x   = (const float*)d_in[0];
    const float* vals= (const float*)d_in[1];
    const float* W0  = (const float*)d_in[2];
    const float* b0  = (const float*)d_in[3];
    const float* g0  = (const float*)d_in[4];
    const float* be0 = (const float*)d_in[5];
    const float* W1  = (const float*)d_in[6];
    const float* b1  = (const float*)d_in[7];
    const float* g1  = (const float*)d_in[8];
    const float* be1 = (const float*)d_in[9];
    const float* W2  = (const float*)d_in[10];
    const float* b2  = (const float*)d_in[11];
    const int* row   = (const int*)d_in[12];
    const int* col   = (const int*)d_in[13];
    const int E = in_sizes[1];
    const int M = in_sizes[0] / 256;
    float* out = (float*)d_out;

    char* ws = (char*)d_ws;
    size_t off = 0;
    auto alloc = [&](size_t bytes) -> void* {
        void* p = ws + off;
        off += (bytes + 255) & ~(size_t)255;
        return p;
    };
    unsigned short* hA = (unsigned short*)alloc((size_t)M * 256 * 2);
    unsigned short* hB = (unsigned short*)alloc((size_t)M * 256 * 2);
    int2*  edges = (int2*)alloc((size_t)E * 8);
    int2*  ebuf  = (int2*)alloc((size_t)E * 8);
    int*   rowptr= (int*)alloc((size_t)(M + 1) * 4);
    float* sums  = (float*)alloc(256 * 4);
    float* sumsq = (float*)alloc(256 * 4);
    float* scale = (float*)alloc(256 * 4);
    float* shift = (float*)alloc(256 * 4);
    short* Wth   = (short*)alloc((size_t)256 * 256 * 2);
    short* Wtl   = (short*)alloc((size_t)256 * 256 * 2);
    const int NB = (M + 511) >> 9;  // buckets of 512 rows (NB<=256 for M<=131072)
    int* hist2d = (int*)alloc((size_t)NB * NBLK_AC * 4);
    int* base2d = (int*)alloc((size_t)NB * NBLK_AC * 4);

    // --- CSR build: atomic-free counting sort ---
    bucket_hist<<<NBLK_AC, 256, 0, stream>>>(row, hist2d, E, NB);
    excl_scan<<<1, 1024, 0, stream>>>(hist2d, base2d, NB * NBLK_AC);
    bucket_scatter<<<NBLK_AC, 256, 0, stream>>>(row, col, vals, base2d, ebuf, E, NB);
    bucket_sort<<<NB, 256, 0, stream>>>(ebuf, base2d, edges, rowptr, E, M, NB);

    int gx = (M + 127) / 128;
    int spmm_grid = (M + 3) / 4;

    // --- layer 0 ---
    wsplit_kernel<<<(256 * 256 + 255) / 256, 256, 0, stream>>>(W0, Wth, Wtl, 256);
    gemm_mfma_kernel<true><<<dim3(gx, 2), 256, 0, stream>>>(x, Wth, Wtl, b0, nullptr, nullptr, hA, M, 256);
    spmm_kernel<256, true><<<spmm_grid, 256, 0, stream>>>(rowptr, edges, hA, hB, M);

    hipMemsetAsync(sums, 0, 2048, stream);
    bn_stats_kernel<<<256, 256, 0, stream>>>(hB, sums, sumsq, M);
    bn_finalize_kernel<<<1, 256, 0, stream>>>(sums, sumsq, g0, be0, scale, shift, M);

    // --- layer 1 ---
    wsplit_kernel<<<(256 * 256 + 255) / 256, 256, 0, stream>>>(W1, Wth, Wtl, 256);
    gemm_mfma_kernel<false><<<dim3(gx, 2), 256, 0, stream>>>(hB, Wth, Wtl, b1, scale, shift, hA, M, 256);
    spmm_kernel<256, true><<<spmm_grid, 256, 0, stream>>>(rowptr, edges, hA, hB, M);

    hipMemsetAsync(sums, 0, 2048, stream);
    bn_stats_kernel<<<256, 256, 0, stream>>>(hB, sums, sumsq, M);
    bn_finalize_kernel<<<1, 256, 0, stream>>>(sums, sumsq, g1, be1, scale, shift, M);

    // --- layer 2 (N=128) ---
    wsplit_kernel<<<(256 * 128 + 255) / 256, 256, 0, stream>>>(W2, Wth, Wtl, 128);
    gemm_mfma_kernel<false><<<dim3(gx, 1), 256, 0, stream>>>(hB, Wth, Wtl, b2, scale, shift, hA, M, 128);
    spmm_kernel<128, false><<<spmm_grid, 256, 0, stream>>>(rowptr, edges, hA, out, M);
}